// Round 12
// baseline (169.032 us; speedup 1.0000x reference)
//
#include <hip/hip_runtime.h>

// Problem constants
#define BB 32
#define CC 1024
#define QQ 64
#define EE 256
#define FE 1024
#define MM (BB*CC)   // 32768

typedef __bf16 bf16_t;
typedef bf16_t bf16x8 __attribute__((ext_vector_type(8)));
typedef float f32x4 __attribute__((ext_vector_type(4)));
typedef unsigned short u16x8 __attribute__((ext_vector_type(8)));

__device__ __forceinline__ unsigned short f2bf(float f) {
  unsigned u = __float_as_uint(f);
  u += 0x7fffu + ((u >> 16) & 1u);   // RNE
  return (unsigned short)(u >> 16);
}
__device__ __forceinline__ float bf2f(unsigned short u) {
  return __uint_as_float(((unsigned)u) << 16);
}

__device__ __forceinline__ void gload_lds16(const void* g, void* l) {
  __builtin_amdgcn_global_load_lds(
      (const __attribute__((address_space(1))) unsigned int*)g,
      (__attribute__((address_space(3))) unsigned int*)l, 16, 0, 0);
}

// ---------------------------------------------------------------- prep: qw = question.w_question; cast W to bf16
__global__ void k_prep(const float* __restrict__ question, const float* __restrict__ w_question,
                       float* __restrict__ qw,
                       const float* __restrict__ W, unsigned short* __restrict__ Wb) {
  int bx = blockIdx.x;
  if (bx < 512) {
    int gid = bx * 256 + threadIdx.x;
    int row = gid >> 6;            // (b*QQ + q), 0..2047
    int lane = gid & 63;
    const float4 q = *(const float4*)(question + (size_t)row * EE + lane * 4);
    const float4 wq = *(const float4*)(w_question + lane * 4);
    float d = q.x*wq.x + q.y*wq.y + q.z*wq.z + q.w*wq.w;
    d += __shfl_xor(d, 1);  d += __shfl_xor(d, 2);  d += __shfl_xor(d, 4);
    d += __shfl_xor(d, 8);  d += __shfl_xor(d, 16); d += __shfl_xor(d, 32);
    if (lane == 0) qw[row] = d;
  } else {
    int i = ((bx - 512) * 256 + threadIdx.x) * 4;
    float4 v = *(const float4*)(W + i);
    ushort4 o; o.x = f2bf(v.x); o.y = f2bf(v.y); o.z = f2bf(v.z); o.w = f2bf(v.w);
    *(ushort4*)(Wb + i) = o;
  }
}

#define DOT4(acc, A, Bv) acc += A.x*Bv.x + A.y*Bv.y + A.z*Bv.z + A.w*Bv.w

// ---------------------------------------------------------------- fused similarity + softmax + PV
__launch_bounds__(256)
__global__ void k_simpv(const float* __restrict__ ctx, const float* __restrict__ question,
                        const float* __restrict__ qw_g, const float* __restrict__ w_context,
                        const float* __restrict__ w_multiple,
                        float* __restrict__ rowmax, unsigned short* __restrict__ att) {
  __shared__ float qbuf[QQ * 132];          // sim: [q][128+4]; PV: [q][64+4]
  __shared__ float ck[64][36];              // ctx*w_mult chunk
  __shared__ unsigned short Pl[QQ][68];     // P[q][c] bf16
  __shared__ float cwl[64];
  __shared__ float qwl[QQ];
  const int tid = threadIdx.x;
  const int b = blockIdx.y;
  const int c0 = blockIdx.x * 64;
  const int tx = tid & 15, ty = tid >> 4;

  const float* qb = question + (size_t)b * (QQ * EE);
  if (tid < QQ) qwl[tid] = qw_g[b * QQ + tid];

  const int cr = tid >> 3, er = (tid & 7) * 4;
  const float* crow0 = ctx + ((size_t)(b * CC + c0 + cr)) * EE;
  const float* crow1 = crow0 + 32 * EE;
  unsigned short* arow0 = att + ((size_t)(b * CC + c0 + cr)) * FE;
  unsigned short* arow1 = arow0 + (size_t)32 * FE;
  float s[4][4] = {{0.f}};
  float cp0 = 0.f, cp1 = 0.f;

  for (int h = 0; h < 2; ++h) {
    if (h) __syncthreads();
    for (int idx = tid * 4; idx < QQ * 128; idx += 1024) {
      int row = idx >> 7, col = idx & 127;
      *(float4*)&qbuf[row * 132 + col] = *(const float4*)(qb + (size_t)row * EE + h * 128 + col);
    }
    for (int eo2 = 0; eo2 < 128; eo2 += 32) {
      const int eo = h * 128 + eo2;
      float4 cv0 = *(const float4*)(crow0 + eo + er);
      float4 cv1 = *(const float4*)(crow1 + eo + er);
      float4 wc = *(const float4*)(w_context + eo + er);
      float4 wm = *(const float4*)(w_multiple + eo + er);
      cp0 += cv0.x*wc.x + cv0.y*wc.y + cv0.z*wc.z + cv0.w*wc.w;
      cp1 += cv1.x*wc.x + cv1.y*wc.y + cv1.z*wc.z + cv1.w*wc.w;
      ushort4 u0, u1;
      u0.x = f2bf(cv0.x); u0.y = f2bf(cv0.y); u0.z = f2bf(cv0.z); u0.w = f2bf(cv0.w);
      u1.x = f2bf(cv1.x); u1.y = f2bf(cv1.y); u1.z = f2bf(cv1.z); u1.w = f2bf(cv1.w);
      *(ushort4*)(arow0 + eo + er) = u0;
      *(ushort4*)(arow1 + eo + er) = u1;
      __syncthreads();
      float4 m0, m1;
      m0.x = cv0.x*wm.x; m0.y = cv0.y*wm.y; m0.z = cv0.z*wm.z; m0.w = cv0.w*wm.w;
      m1.x = cv1.x*wm.x; m1.y = cv1.y*wm.y; m1.z = cv1.z*wm.z; m1.w = cv1.w*wm.w;
      *(float4*)&ck[cr][er] = m0;
      *(float4*)&ck[cr + 32][er] = m1;
      __syncthreads();
#pragma unroll
      for (int ee = 0; ee < 32; ee += 4) {
        float4 a0 = *(const float4*)&ck[ty +  0][ee];
        float4 a1 = *(const float4*)&ck[ty + 16][ee];
        float4 a2 = *(const float4*)&ck[ty + 32][ee];
        float4 a3 = *(const float4*)&ck[ty + 48][ee];
        float4 b0 = *(const float4*)&qbuf[(tx +  0) * 132 + eo2 + ee];
        float4 b1 = *(const float4*)&qbuf[(tx + 16) * 132 + eo2 + ee];
        float4 b2 = *(const float4*)&qbuf[(tx + 32) * 132 + eo2 + ee];
        float4 b3 = *(const float4*)&qbuf[(tx + 48) * 132 + eo2 + ee];
        DOT4(s[0][0], a0, b0); DOT4(s[0][1], a0, b1); DOT4(s[0][2], a0, b2); DOT4(s[0][3], a0, b3);
        DOT4(s[1][0], a1, b0); DOT4(s[1][1], a1, b1); DOT4(s[1][2], a1, b2); DOT4(s[1][3], a1, b3);
        DOT4(s[2][0], a2, b0); DOT4(s[2][1], a2, b1); DOT4(s[2][2], a2, b2); DOT4(s[2][3], a2, b3);
        DOT4(s[3][0], a3, b0); DOT4(s[3][1], a3, b1); DOT4(s[3][2], a3, b2); DOT4(s[3][3], a3, b3);
      }
    }
  }
  cp0 += __shfl_xor(cp0, 1); cp0 += __shfl_xor(cp0, 2); cp0 += __shfl_xor(cp0, 4);
  cp1 += __shfl_xor(cp1, 1); cp1 += __shfl_xor(cp1, 2); cp1 += __shfl_xor(cp1, 4);
  if ((tid & 7) == 0) { cwl[cr] = cp0; cwl[cr + 32] = cp1; }
  __syncthreads();

#pragma unroll
  for (int i = 0; i < 4; ++i) {
    int c = ty + 16 * i;
    float cw = cwl[c];
    float f[4], mx = -1e30f;
#pragma unroll
    for (int j = 0; j < 4; ++j) {
      f[j] = s[i][j] + cw + qwl[tx + 16 * j];
      mx = fmaxf(mx, f[j]);
    }
    mx = fmaxf(mx, __shfl_xor(mx, 1));
    mx = fmaxf(mx, __shfl_xor(mx, 2));
    mx = fmaxf(mx, __shfl_xor(mx, 4));
    mx = fmaxf(mx, __shfl_xor(mx, 8));
    float sum = 0.f;
#pragma unroll
    for (int j = 0; j < 4; ++j) { f[j] = expf(f[j] - mx); sum += f[j]; }
    sum += __shfl_xor(sum, 1);
    sum += __shfl_xor(sum, 2);
    sum += __shfl_xor(sum, 4);
    sum += __shfl_xor(sum, 8);
    float inv = 1.f / sum;
    if (tx == 0) rowmax[(size_t)b * CC + c0 + c] = mx;
#pragma unroll
    for (int j = 0; j < 4; ++j) Pl[tx + 16 * j][c] = f2bf(f[j] * inv);
  }
  __syncthreads();

  for (int ep = 0; ep < EE; ep += 64) {
    if (ep) __syncthreads();
    {
      int q = tid >> 2, e16 = (tid & 3) * 16;
      const float* src = qb + (size_t)q * EE + ep + e16;
      *(float4*)&qbuf[q * 68 + e16 +  0] = *(const float4*)(src);
      *(float4*)&qbuf[q * 68 + e16 +  4] = *(const float4*)(src + 4);
      *(float4*)&qbuf[q * 68 + e16 +  8] = *(const float4*)(src + 8);
      *(float4*)&qbuf[q * 68 + e16 + 12] = *(const float4*)(src + 12);
    }
    __syncthreads();
    float s2[4][4] = {{0.f}};
#pragma unroll 8
    for (int q = 0; q < QQ; ++q) {
      float a0 = bf2f(Pl[q][ty +  0]);
      float a1 = bf2f(Pl[q][ty + 16]);
      float a2 = bf2f(Pl[q][ty + 32]);
      float a3 = bf2f(Pl[q][ty + 48]);
      float4 bv = *(const float4*)&qbuf[q * 68 + tx * 4];
      s2[0][0] += a0 * bv.x; s2[0][1] += a0 * bv.y; s2[0][2] += a0 * bv.z; s2[0][3] += a0 * bv.w;
      s2[1][0] += a1 * bv.x; s2[1][1] += a1 * bv.y; s2[1][2] += a1 * bv.z; s2[1][3] += a1 * bv.w;
      s2[2][0] += a2 * bv.x; s2[2][1] += a2 * bv.y; s2[2][2] += a2 * bv.z; s2[2][3] += a2 * bv.w;
      s2[3][0] += a3 * bv.x; s2[3][1] += a3 * bv.y; s2[3][2] += a3 * bv.z; s2[3][3] += a3 * bv.w;
    }
#pragma unroll
    for (int i = 0; i < 4; ++i) {
      int c = ty + 16 * i;
      size_t row = (size_t)(b * CC + c0 + c);
      unsigned short* arow = att + row * (size_t)FE;
      ushort4 cu = *(const ushort4*)(arow + ep + tx * 4);
      float cx = bf2f(cu.x), cy = bf2f(cu.y), cz = bf2f(cu.z), cw = bf2f(cu.w);
      ushort4 o1, o2;
      o1.x = f2bf(s2[i][0]);       o1.y = f2bf(s2[i][1]);       o1.z = f2bf(s2[i][2]);       o1.w = f2bf(s2[i][3]);
      o2.x = f2bf(cx * s2[i][0]);  o2.y = f2bf(cy * s2[i][1]);  o2.z = f2bf(cz * s2[i][2]);  o2.w = f2bf(cw * s2[i][3]);
      *(ushort4*)(arow + 1 * EE + ep + tx * 4) = o1;
      *(ushort4*)(arow + 2 * EE + ep + tx * 4) = o2;
    }
  }
}

// ---------------------------------------------------------------- q2c: softmax over c of rowmax
__global__ void k_q2c_softmax(const float* __restrict__ rowmax, float* __restrict__ q2cw) {
  int b = blockIdx.x, tid = threadIdx.x;
  __shared__ float rbuf[4], sbuf[4];
  float4 v = *(const float4*)(rowmax + (size_t)b * CC + tid * 4);
  float m = fmaxf(fmaxf(v.x, v.y), fmaxf(v.z, v.w));
  for (int off = 1; off < 64; off <<= 1) m = fmaxf(m, __shfl_xor(m, off));
  int wv = tid >> 6;
  if ((tid & 63) == 0) rbuf[wv] = m;
  __syncthreads();
  m = fmaxf(fmaxf(rbuf[0], rbuf[1]), fmaxf(rbuf[2], rbuf[3]));
  float e0 = expf(v.x - m), e1 = expf(v.y - m), e2 = expf(v.z - m), e3 = expf(v.w - m);
  float sum = e0 + e1 + e2 + e3;
  for (int off = 1; off < 64; off <<= 1) sum += __shfl_xor(sum, off);
  if ((tid & 63) == 0) sbuf[wv] = sum;
  __syncthreads();
  sum = sbuf[0] + sbuf[1] + sbuf[2] + sbuf[3];
  float inv = 1.f / sum;
  float4 o; o.x = e0 * inv; o.y = e1 * inv; o.z = e2 * inv; o.w = e3 * inv;
  *(float4*)(q2cw + (size_t)b * CC + tid * 4) = o;
}

// ---------------------------------------------------------------- q2c_att partials: sum_c w[c]*ctx_bf16[b,c,e]
__global__ void k_q2c_part(const unsigned short* __restrict__ att, const float* __restrict__ w,
                           float* __restrict__ part) {
  int b = blockIdx.y, ch = blockIdx.x;
  int e = threadIdx.x;
  const unsigned short* base = att + ((size_t)(b * CC + ch * 128)) * FE + e;
  const float* wp = w + b * CC + ch * 128;
  float acc = 0.f;
#pragma unroll 4
  for (int c = 0; c < 128; ++c) acc += wp[c] * bf2f(base[(size_t)c * FE]);
  part[(b * 8 + ch) * EE + e] = acc;
}

// ---------------------------------------------------------------- final GEMM: out = attended @ W^T + b, masked
// m97 configuration: 128x128 tile, BK=32, single-buffered 17.4KB LDS, 4 waves,
// 2-barrier loop. __launch_bounds__(256,4): 4 blocks/CU (16 waves) — the only
// resource cap at 3 was the previous launch_bounds itself (regs 124<=128, LDS 70KB<=160).
// Fused q2c-sum prologue + on-the-fly att3 for K-tiles 12..15.
__launch_bounds__(256, 4)
__global__ void k_gemm(const unsigned short* __restrict__ A, const unsigned short* __restrict__ Bw,
                       const float* __restrict__ part, const float* __restrict__ bias,
                       const float* __restrict__ mask, float* __restrict__ out) {
  __shared__ bf16_t As[128][32];
  __shared__ bf16_t Bs[128][32];
  __shared__ float q2cl[EE];                // this batch's q2c_att (fp32)
  const int tid = threadIdx.x;
  const int lane = tid & 63;
  const int wave = tid >> 6;
  const int wr = wave >> 1, wc = wave & 1;

  // XCD-chunked swizzle: 2048 blocks, 8 XCDs -> 256 contiguous wgs per XCD.
  const int bid = blockIdx.x;
  const int wg = (bid & 7) * 256 + (bid >> 3);
  const int bcol = (wg & 7) * 128;
  const int brow = (wg >> 3) * 128;
  const int bb = brow >> 10;                // batch index (128-row tile never crosses batch)

  const int r = lane & 15, kg = lane >> 4;
  const int rk = (kg ^ ((r >> 2) & 3)) * 8; // swizzled k-granule for frag reads

  // staging: one 16B granule per thread per instr; dest linear in tid.
  const int srow = tid >> 2;                // 0..63
  const int sgr = tid & 3;                  // granule 0..3
  const int ssw = (sgr ^ ((srow >> 2) & 3)) * 8;  // pre-swizzled source granule
  const unsigned short* gA0 = A  + (size_t)(brow + srow) * FE + ssw;
  const unsigned short* gA1 = gA0 + (size_t)64 * FE;
  const unsigned short* gB0 = Bw + (size_t)(bcol + srow) * FE + ssw;
  const unsigned short* gB1 = gB0 + (size_t)64 * FE;
  bf16_t* dA0 = &As[srow][sgr * 8];
  bf16_t* dA1 = dA0 + 64 * 32;
  bf16_t* dB0 = &Bs[srow][sgr * 8];
  bf16_t* dB1 = dB0 + 64 * 32;

  // prologue: reduce part -> q2cl (first consumer is k0=768, many barriers later)
  {
    float a = 0.f;
#pragma unroll
    for (int ch = 0; ch < 8; ++ch) a += part[(bb * 8 + ch) * EE + tid];
    q2cl[tid] = a;
  }

  f32x4 acc[4][4] = {};

  for (int k0 = 0; k0 < FE; k0 += 32) {
    if (k0 < 768) {
      gload_lds16(gA0 + k0, dA0);
      gload_lds16(gA1 + k0, dA1);
    } else {
      // fused att3: A granule = bf16( bf2f(att0) * q2c )
      const int e0 = k0 - 768;
      u16x8 va = *(const u16x8*)(gA0 + e0);
      u16x8 vb = *(const u16x8*)(gA1 + e0);
      float4 g0 = *(const float4*)&q2cl[e0 + ssw];
      float4 g1 = *(const float4*)&q2cl[e0 + ssw + 4];
      u16x8 oa, ob;
      oa[0] = f2bf(bf2f(va[0]) * g0.x); oa[1] = f2bf(bf2f(va[1]) * g0.y);
      oa[2] = f2bf(bf2f(va[2]) * g0.z); oa[3] = f2bf(bf2f(va[3]) * g0.w);
      oa[4] = f2bf(bf2f(va[4]) * g1.x); oa[5] = f2bf(bf2f(va[5]) * g1.y);
      oa[6] = f2bf(bf2f(va[6]) * g1.z); oa[7] = f2bf(bf2f(va[7]) * g1.w);
      ob[0] = f2bf(bf2f(vb[0]) * g0.x); ob[1] = f2bf(bf2f(vb[1]) * g0.y);
      ob[2] = f2bf(bf2f(vb[2]) * g0.z); ob[3] = f2bf(bf2f(vb[3]) * g0.w);
      ob[4] = f2bf(bf2f(vb[4]) * g1.x); ob[5] = f2bf(bf2f(vb[5]) * g1.y);
      ob[6] = f2bf(bf2f(vb[6]) * g1.z); ob[7] = f2bf(bf2f(vb[7]) * g1.w);
      *(u16x8*)dA0 = oa;
      *(u16x8*)dA1 = ob;
    }
    gload_lds16(gB0 + k0, dB0);
    gload_lds16(gB1 + k0, dB1);
    __syncthreads();                       // drains vmcnt+lgkmcnt: tile ready
    bf16x8 fa[4], fb[4];
#pragma unroll
    for (int m = 0; m < 4; ++m) fa[m] = *(const bf16x8*)&As[wr * 64 + m * 16 + r][rk];
#pragma unroll
    for (int n = 0; n < 4; ++n) fb[n] = *(const bf16x8*)&Bs[wc * 64 + n * 16 + r][rk];
#pragma unroll
    for (int m = 0; m < 4; ++m)
#pragma unroll
      for (int n = 0; n < 4; ++n)
        acc[m][n] = __builtin_amdgcn_mfma_f32_16x16x32_bf16(fa[m], fb[n], acc[m][n], 0, 0, 0);
    __syncthreads();                       // all reads done before next-iter overwrite
  }

#pragma unroll
  for (int m = 0; m < 4; ++m) {
#pragma unroll
    for (int n = 0; n < 4; ++n) {
#pragma unroll
      for (int reg = 0; reg < 4; ++reg) {
        int row = brow + wr * 64 + m * 16 + kg * 4 + reg;
        int col = bcol + wc * 64 + n * 16 + r;
        out[(size_t)row * FE + col] = (acc[m][n][reg] + bias[col]) * mask[row];
      }
    }
  }
}

// ---------------------------------------------------------------- launch
extern "C" void kernel_launch(void* const* d_in, const int* in_sizes, int n_in,
                              void* d_out, int out_size, void* d_ws, size_t ws_size,
                              hipStream_t stream) {
  const float* ctx  = (const float*)d_in[0];
  const float* ques = (const float*)d_in[1];
  const float* mask = (const float*)d_in[2];
  const float* w_q  = (const float*)d_in[3];
  const float* w_c  = (const float*)d_in[4];
  const float* w_m  = (const float*)d_in[5];
  const float* fW   = (const float*)d_in[6];
  const float* fb   = (const float*)d_in[7];
  float* out = (float*)d_out;

  char* ws = (char*)d_ws;
  float* qw     = (float*)(ws);                        //     8,192 B
  float* rowmax = (float*)(ws + 8192);                 //   131,072 B
  float* q2cw   = (float*)(ws + 139264);               //   131,072 B
  float* part   = (float*)(ws + 270336);               //   262,144 B
  unsigned short* attended = (unsigned short*)(ws + 1048576);   // 67,108,864 B
  unsigned short* Wb       = (unsigned short*)(ws + 68157440);  //  2,097,152 B

  k_prep<<<1536, 256, 0, stream>>>(ques, w_q, qw, fW, Wb);
  k_simpv<<<dim3(16, 32), 256, 0, stream>>>(ctx, ques, qw, w_c, w_m, rowmax, attended);
  k_q2c_softmax<<<32, 256, 0, stream>>>(rowmax, q2cw);
  k_q2c_part<<<dim3(8, 32), 256, 0, stream>>>(attended, q2cw, part);
  k_gemm<<<2048, 256, 0, stream>>>(attended, Wb, part, fb, mask, out);
}

// Round 13
// 159.129 us; speedup vs baseline: 1.0622x; 1.0622x over previous
//
#include <hip/hip_runtime.h>

// Problem constants
#define BB 32
#define CC 1024
#define QQ 64
#define EE 256
#define FE 1024
#define MM (BB*CC)   // 32768

typedef __bf16 bf16_t;
typedef bf16_t bf16x8 __attribute__((ext_vector_type(8)));
typedef float f32x4 __attribute__((ext_vector_type(4)));
typedef unsigned short u16x8 __attribute__((ext_vector_type(8)));

__device__ __forceinline__ unsigned short f2bf(float f) {
  unsigned u = __float_as_uint(f);
  u += 0x7fffu + ((u >> 16) & 1u);   // RNE
  return (unsigned short)(u >> 16);
}
__device__ __forceinline__ float bf2f(unsigned short u) {
  return __uint_as_float(((unsigned)u) << 16);
}

__device__ __forceinline__ void gload_lds16(const void* g, void* l) {
  __builtin_amdgcn_global_load_lds(
      (const __attribute__((address_space(1))) unsigned int*)g,
      (__attribute__((address_space(3))) unsigned int*)l, 16, 0, 0);
}

// ---------------------------------------------------------------- prep: qw = question.w_question; cast W to bf16
__global__ void k_prep(const float* __restrict__ question, const float* __restrict__ w_question,
                       float* __restrict__ qw,
                       const float* __restrict__ W, unsigned short* __restrict__ Wb) {
  int bx = blockIdx.x;
  if (bx < 512) {
    int gid = bx * 256 + threadIdx.x;
    int row = gid >> 6;            // (b*QQ + q), 0..2047
    int lane = gid & 63;
    const float4 q = *(const float4*)(question + (size_t)row * EE + lane * 4);
    const float4 wq = *(const float4*)(w_question + lane * 4);
    float d = q.x*wq.x + q.y*wq.y + q.z*wq.z + q.w*wq.w;
    d += __shfl_xor(d, 1);  d += __shfl_xor(d, 2);  d += __shfl_xor(d, 4);
    d += __shfl_xor(d, 8);  d += __shfl_xor(d, 16); d += __shfl_xor(d, 32);
    if (lane == 0) qw[row] = d;
  } else {
    int i = ((bx - 512) * 256 + threadIdx.x) * 4;
    float4 v = *(const float4*)(W + i);
    ushort4 o; o.x = f2bf(v.x); o.y = f2bf(v.y); o.z = f2bf(v.z); o.w = f2bf(v.w);
    *(ushort4*)(Wb + i) = o;
  }
}

#define DOT4(acc, A, Bv) acc += A.x*Bv.x + A.y*Bv.y + A.z*Bv.z + A.w*Bv.w

// ---------------------------------------------------------------- fused similarity + softmax + PV
__launch_bounds__(256)
__global__ void k_simpv(const float* __restrict__ ctx, const float* __restrict__ question,
                        const float* __restrict__ qw_g, const float* __restrict__ w_context,
                        const float* __restrict__ w_multiple,
                        float* __restrict__ rowmax, unsigned short* __restrict__ att) {
  __shared__ float qbuf[QQ * 132];          // sim: [q][128+4]; PV: [q][64+4]
  __shared__ float ck[64][36];              // ctx*w_mult chunk
  __shared__ unsigned short Pl[QQ][68];     // P[q][c] bf16
  __shared__ float cwl[64];
  __shared__ float qwl[QQ];
  const int tid = threadIdx.x;
  const int b = blockIdx.y;
  const int c0 = blockIdx.x * 64;
  const int tx = tid & 15, ty = tid >> 4;

  const float* qb = question + (size_t)b * (QQ * EE);
  if (tid < QQ) qwl[tid] = qw_g[b * QQ + tid];

  const int cr = tid >> 3, er = (tid & 7) * 4;
  const float* crow0 = ctx + ((size_t)(b * CC + c0 + cr)) * EE;
  const float* crow1 = crow0 + 32 * EE;
  unsigned short* arow0 = att + ((size_t)(b * CC + c0 + cr)) * FE;
  unsigned short* arow1 = arow0 + (size_t)32 * FE;
  float s[4][4] = {{0.f}};
  float cp0 = 0.f, cp1 = 0.f;

  for (int h = 0; h < 2; ++h) {
    if (h) __syncthreads();
    for (int idx = tid * 4; idx < QQ * 128; idx += 1024) {
      int row = idx >> 7, col = idx & 127;
      *(float4*)&qbuf[row * 132 + col] = *(const float4*)(qb + (size_t)row * EE + h * 128 + col);
    }
    for (int eo2 = 0; eo2 < 128; eo2 += 32) {
      const int eo = h * 128 + eo2;
      float4 cv0 = *(const float4*)(crow0 + eo + er);
      float4 cv1 = *(const float4*)(crow1 + eo + er);
      float4 wc = *(const float4*)(w_context + eo + er);
      float4 wm = *(const float4*)(w_multiple + eo + er);
      cp0 += cv0.x*wc.x + cv0.y*wc.y + cv0.z*wc.z + cv0.w*wc.w;
      cp1 += cv1.x*wc.x + cv1.y*wc.y + cv1.z*wc.z + cv1.w*wc.w;
      ushort4 u0, u1;
      u0.x = f2bf(cv0.x); u0.y = f2bf(cv0.y); u0.z = f2bf(cv0.z); u0.w = f2bf(cv0.w);
      u1.x = f2bf(cv1.x); u1.y = f2bf(cv1.y); u1.z = f2bf(cv1.z); u1.w = f2bf(cv1.w);
      *(ushort4*)(arow0 + eo + er) = u0;
      *(ushort4*)(arow1 + eo + er) = u1;
      __syncthreads();
      float4 m0, m1;
      m0.x = cv0.x*wm.x; m0.y = cv0.y*wm.y; m0.z = cv0.z*wm.z; m0.w = cv0.w*wm.w;
      m1.x = cv1.x*wm.x; m1.y = cv1.y*wm.y; m1.z = cv1.z*wm.z; m1.w = cv1.w*wm.w;
      *(float4*)&ck[cr][er] = m0;
      *(float4*)&ck[cr + 32][er] = m1;
      __syncthreads();
#pragma unroll
      for (int ee = 0; ee < 32; ee += 4) {
        float4 a0 = *(const float4*)&ck[ty +  0][ee];
        float4 a1 = *(const float4*)&ck[ty + 16][ee];
        float4 a2 = *(const float4*)&ck[ty + 32][ee];
        float4 a3 = *(const float4*)&ck[ty + 48][ee];
        float4 b0 = *(const float4*)&qbuf[(tx +  0) * 132 + eo2 + ee];
        float4 b1 = *(const float4*)&qbuf[(tx + 16) * 132 + eo2 + ee];
        float4 b2 = *(const float4*)&qbuf[(tx + 32) * 132 + eo2 + ee];
        float4 b3 = *(const float4*)&qbuf[(tx + 48) * 132 + eo2 + ee];
        DOT4(s[0][0], a0, b0); DOT4(s[0][1], a0, b1); DOT4(s[0][2], a0, b2); DOT4(s[0][3], a0, b3);
        DOT4(s[1][0], a1, b0); DOT4(s[1][1], a1, b1); DOT4(s[1][2], a1, b2); DOT4(s[1][3], a1, b3);
        DOT4(s[2][0], a2, b0); DOT4(s[2][1], a2, b1); DOT4(s[2][2], a2, b2); DOT4(s[2][3], a2, b3);
        DOT4(s[3][0], a3, b0); DOT4(s[3][1], a3, b1); DOT4(s[3][2], a3, b2); DOT4(s[3][3], a3, b3);
      }
    }
  }
  cp0 += __shfl_xor(cp0, 1); cp0 += __shfl_xor(cp0, 2); cp0 += __shfl_xor(cp0, 4);
  cp1 += __shfl_xor(cp1, 1); cp1 += __shfl_xor(cp1, 2); cp1 += __shfl_xor(cp1, 4);
  if ((tid & 7) == 0) { cwl[cr] = cp0; cwl[cr + 32] = cp1; }
  __syncthreads();

#pragma unroll
  for (int i = 0; i < 4; ++i) {
    int c = ty + 16 * i;
    float cw = cwl[c];
    float f[4], mx = -1e30f;
#pragma unroll
    for (int j = 0; j < 4; ++j) {
      f[j] = s[i][j] + cw + qwl[tx + 16 * j];
      mx = fmaxf(mx, f[j]);
    }
    mx = fmaxf(mx, __shfl_xor(mx, 1));
    mx = fmaxf(mx, __shfl_xor(mx, 2));
    mx = fmaxf(mx, __shfl_xor(mx, 4));
    mx = fmaxf(mx, __shfl_xor(mx, 8));
    float sum = 0.f;
#pragma unroll
    for (int j = 0; j < 4; ++j) { f[j] = expf(f[j] - mx); sum += f[j]; }
    sum += __shfl_xor(sum, 1);
    sum += __shfl_xor(sum, 2);
    sum += __shfl_xor(sum, 4);
    sum += __shfl_xor(sum, 8);
    float inv = 1.f / sum;
    if (tx == 0) rowmax[(size_t)b * CC + c0 + c] = mx;
#pragma unroll
    for (int j = 0; j < 4; ++j) Pl[tx + 16 * j][c] = f2bf(f[j] * inv);
  }
  __syncthreads();

  for (int ep = 0; ep < EE; ep += 64) {
    if (ep) __syncthreads();
    {
      int q = tid >> 2, e16 = (tid & 3) * 16;
      const float* src = qb + (size_t)q * EE + ep + e16;
      *(float4*)&qbuf[q * 68 + e16 +  0] = *(const float4*)(src);
      *(float4*)&qbuf[q * 68 + e16 +  4] = *(const float4*)(src + 4);
      *(float4*)&qbuf[q * 68 + e16 +  8] = *(const float4*)(src + 8);
      *(float4*)&qbuf[q * 68 + e16 + 12] = *(const float4*)(src + 12);
    }
    __syncthreads();
    float s2[4][4] = {{0.f}};
#pragma unroll 8
    for (int q = 0; q < QQ; ++q) {
      float a0 = bf2f(Pl[q][ty +  0]);
      float a1 = bf2f(Pl[q][ty + 16]);
      float a2 = bf2f(Pl[q][ty + 32]);
      float a3 = bf2f(Pl[q][ty + 48]);
      float4 bv = *(const float4*)&qbuf[q * 68 + tx * 4];
      s2[0][0] += a0 * bv.x; s2[0][1] += a0 * bv.y; s2[0][2] += a0 * bv.z; s2[0][3] += a0 * bv.w;
      s2[1][0] += a1 * bv.x; s2[1][1] += a1 * bv.y; s2[1][2] += a1 * bv.z; s2[1][3] += a1 * bv.w;
      s2[2][0] += a2 * bv.x; s2[2][1] += a2 * bv.y; s2[2][2] += a2 * bv.z; s2[2][3] += a2 * bv.w;
      s2[3][0] += a3 * bv.x; s2[3][1] += a3 * bv.y; s2[3][2] += a3 * bv.z; s2[3][3] += a3 * bv.w;
    }
#pragma unroll
    for (int i = 0; i < 4; ++i) {
      int c = ty + 16 * i;
      size_t row = (size_t)(b * CC + c0 + c);
      unsigned short* arow = att + row * (size_t)FE;
      ushort4 cu = *(const ushort4*)(arow + ep + tx * 4);
      float cx = bf2f(cu.x), cy = bf2f(cu.y), cz = bf2f(cu.z), cw = bf2f(cu.w);
      ushort4 o1, o2;
      o1.x = f2bf(s2[i][0]);       o1.y = f2bf(s2[i][1]);       o1.z = f2bf(s2[i][2]);       o1.w = f2bf(s2[i][3]);
      o2.x = f2bf(cx * s2[i][0]);  o2.y = f2bf(cy * s2[i][1]);  o2.z = f2bf(cz * s2[i][2]);  o2.w = f2bf(cw * s2[i][3]);
      *(ushort4*)(arow + 1 * EE + ep + tx * 4) = o1;
      *(ushort4*)(arow + 2 * EE + ep + tx * 4) = o2;
    }
  }
}

// ---------------------------------------------------------------- q2c: softmax over c of rowmax
__global__ void k_q2c_softmax(const float* __restrict__ rowmax, float* __restrict__ q2cw) {
  int b = blockIdx.x, tid = threadIdx.x;
  __shared__ float rbuf[4], sbuf[4];
  float4 v = *(const float4*)(rowmax + (size_t)b * CC + tid * 4);
  float m = fmaxf(fmaxf(v.x, v.y), fmaxf(v.z, v.w));
  for (int off = 1; off < 64; off <<= 1) m = fmaxf(m, __shfl_xor(m, off));
  int wv = tid >> 6;
  if ((tid & 63) == 0) rbuf[wv] = m;
  __syncthreads();
  m = fmaxf(fmaxf(rbuf[0], rbuf[1]), fmaxf(rbuf[2], rbuf[3]));
  float e0 = expf(v.x - m), e1 = expf(v.y - m), e2 = expf(v.z - m), e3 = expf(v.w - m);
  float sum = e0 + e1 + e2 + e3;
  for (int off = 1; off < 64; off <<= 1) sum += __shfl_xor(sum, off);
  if ((tid & 63) == 0) sbuf[wv] = sum;
  __syncthreads();
  sum = sbuf[0] + sbuf[1] + sbuf[2] + sbuf[3];
  float inv = 1.f / sum;
  float4 o; o.x = e0 * inv; o.y = e1 * inv; o.z = e2 * inv; o.w = e3 * inv;
  *(float4*)(q2cw + (size_t)b * CC + tid * 4) = o;
}

// ---------------------------------------------------------------- q2c_att partials: sum_c w[c]*ctx_bf16[b,c,e]
__global__ void k_q2c_part(const unsigned short* __restrict__ att, const float* __restrict__ w,
                           float* __restrict__ part) {
  int b = blockIdx.y, ch = blockIdx.x;
  int e = threadIdx.x;
  const unsigned short* base = att + ((size_t)(b * CC + ch * 128)) * FE + e;
  const float* wp = w + b * CC + ch * 128;
  float acc = 0.f;
#pragma unroll 4
  for (int c = 0; c < 128; ++c) acc += wp[c] * bf2f(base[(size_t)c * FE]);
  part[(b * 8 + ch) * EE + e] = acc;
}

// ---------------------------------------------------------------- Wmod: att[b*1024+n][768:1024] = bf16(W[n][e] + W[n][768+e]*q2c_b[e])
// Folds att3's GEMM contribution into per-batch weights: att3 @ W4^T = att0 @ (W4 .* q2c_b)^T,
// so gemm K shrinks 1024 -> 768. Wmod_b stored in att's unused quarter-3 (rows b*1024+n).
__global__ void k_wmod(const unsigned short* __restrict__ Wb, const float* __restrict__ part,
                       unsigned short* __restrict__ att) {
  __shared__ float q2cl[EE];
  const int b = blockIdx.y;
  const int t = threadIdx.x;
  {
    float a = 0.f;
#pragma unroll
    for (int ch = 0; ch < 8; ++ch) a += part[(b * 8 + ch) * EE + t];
    q2cl[t] = a;
  }
  __syncthreads();
  const int n = blockIdx.x * 8 + (t >> 5);
  const int e = (t & 31) * 8;
  u16x8 w1 = *(const u16x8*)(Wb + (size_t)n * FE + e);
  u16x8 w4 = *(const u16x8*)(Wb + (size_t)n * FE + 768 + e);
  float4 g0 = *(const float4*)&q2cl[e];
  float4 g1 = *(const float4*)&q2cl[e + 4];
  u16x8 o;
  o[0] = f2bf(bf2f(w1[0]) + bf2f(w4[0]) * g0.x);
  o[1] = f2bf(bf2f(w1[1]) + bf2f(w4[1]) * g0.y);
  o[2] = f2bf(bf2f(w1[2]) + bf2f(w4[2]) * g0.z);
  o[3] = f2bf(bf2f(w1[3]) + bf2f(w4[3]) * g0.w);
  o[4] = f2bf(bf2f(w1[4]) + bf2f(w4[4]) * g1.x);
  o[5] = f2bf(bf2f(w1[5]) + bf2f(w4[5]) * g1.y);
  o[6] = f2bf(bf2f(w1[6]) + bf2f(w4[6]) * g1.z);
  o[7] = f2bf(bf2f(w1[7]) + bf2f(w4[7]) * g1.w);
  *(u16x8*)(att + ((size_t)(b * CC + n)) * FE + 768 + e) = o;
}

// ---------------------------------------------------------------- final GEMM: out = A[:,0:768] @ B^T + bias, masked
// K=768: B rows = [Wmod_b (k<256, from att q3), W[:,256:768] (from Wb)].
// m97 config: 128x128 tile, BK=32, single-buffered 16KB LDS, 4 waves, 2-barrier loop, 3 blk/CU.
__launch_bounds__(256, 3)
__global__ void k_gemm(const unsigned short* __restrict__ A, const unsigned short* __restrict__ Bw,
                       const float* __restrict__ bias, const float* __restrict__ mask,
                       float* __restrict__ out) {
  __shared__ bf16_t As[128][32];
  __shared__ bf16_t Bs[128][32];
  const int tid = threadIdx.x;
  const int lane = tid & 63;
  const int wave = tid >> 6;
  const int wr = wave >> 1, wc = wave & 1;

  // XCD-chunked swizzle: 2048 blocks, 8 XCDs -> 256 contiguous wgs per XCD.
  const int bid = blockIdx.x;
  const int wg = (bid & 7) * 256 + (bid >> 3);
  const int bcol = (wg & 7) * 128;
  const int brow = (wg >> 3) * 128;
  const int bb = brow >> 10;                // batch index (128-row tile never crosses batch)

  const int r = lane & 15, kg = lane >> 4;
  const int rk = (kg ^ ((r >> 2) & 3)) * 8; // swizzled k-granule for frag reads

  // staging: one 16B granule per thread per instr; dest linear in tid.
  const int srow = tid >> 2;                // 0..63
  const int sgr = tid & 3;                  // granule 0..3
  const int ssw = (sgr ^ ((srow >> 2) & 3)) * 8;  // pre-swizzled source granule
  const unsigned short* gA0 = A + (size_t)(brow + srow) * FE + ssw;
  const unsigned short* gA1 = gA0 + (size_t)64 * FE;
  // B for k0 >= 256: original W columns (Wb, stride FE)
  const unsigned short* gB0 = Bw + (size_t)(bcol + srow) * FE + ssw;
  const unsigned short* gB1 = gB0 + (size_t)64 * FE;
  // B for k0 < 256: Wmod_b, stored in att quarter-3 of rows (bb*1024 + n)
  const unsigned short* gW0 = A + (size_t)(bb * CC + bcol + srow) * FE + 768 + ssw;
  const unsigned short* gW1 = gW0 + (size_t)64 * FE;
  bf16_t* dA0 = &As[srow][sgr * 8];
  bf16_t* dA1 = dA0 + 64 * 32;
  bf16_t* dB0 = &Bs[srow][sgr * 8];
  bf16_t* dB1 = dB0 + 64 * 32;

  f32x4 acc[4][4] = {};

  for (int k0 = 0; k0 < 768; k0 += 32) {
    gload_lds16(gA0 + k0, dA0);
    gload_lds16(gA1 + k0, dA1);
    if (k0 < 256) {
      gload_lds16(gW0 + k0, dB0);
      gload_lds16(gW1 + k0, dB1);
    } else {
      gload_lds16(gB0 + k0, dB0);
      gload_lds16(gB1 + k0, dB1);
    }
    __syncthreads();                       // drains vmcnt: tile ready
    bf16x8 fa[4], fb[4];
#pragma unroll
    for (int m = 0; m < 4; ++m) fa[m] = *(const bf16x8*)&As[wr * 64 + m * 16 + r][rk];
#pragma unroll
    for (int n = 0; n < 4; ++n) fb[n] = *(const bf16x8*)&Bs[wc * 64 + n * 16 + r][rk];
#pragma unroll
    for (int m = 0; m < 4; ++m)
#pragma unroll
      for (int n = 0; n < 4; ++n)
        acc[m][n] = __builtin_amdgcn_mfma_f32_16x16x32_bf16(fa[m], fb[n], acc[m][n], 0, 0, 0);
    __syncthreads();                       // all reads done before next-iter overwrite
  }

#pragma unroll
  for (int m = 0; m < 4; ++m) {
#pragma unroll
    for (int n = 0; n < 4; ++n) {
#pragma unroll
      for (int reg = 0; reg < 4; ++reg) {
        int row = brow + wr * 64 + m * 16 + kg * 4 + reg;
        int col = bcol + wc * 64 + n * 16 + r;
        out[(size_t)row * FE + col] = (acc[m][n][reg] + bias[col]) * mask[row];
      }
    }
  }
}

// ---------------------------------------------------------------- launch
extern "C" void kernel_launch(void* const* d_in, const int* in_sizes, int n_in,
                              void* d_out, int out_size, void* d_ws, size_t ws_size,
                              hipStream_t stream) {
  const float* ctx  = (const float*)d_in[0];
  const float* ques = (const float*)d_in[1];
  const float* mask = (const float*)d_in[2];
  const float* w_q  = (const float*)d_in[3];
  const float* w_c  = (const float*)d_in[4];
  const float* w_m  = (const float*)d_in[5];
  const float* fW   = (const float*)d_in[6];
  const float* fb   = (const float*)d_in[7];
  float* out = (float*)d_out;

  char* ws = (char*)d_ws;
  float* qw     = (float*)(ws);                        //     8,192 B
  float* rowmax = (float*)(ws + 8192);                 //   131,072 B
  float* q2cw   = (float*)(ws + 139264);               //   131,072 B
  float* part   = (float*)(ws + 270336);               //   262,144 B
  unsigned short* attended = (unsigned short*)(ws + 1048576);   // 67,108,864 B (q3 holds Wmod)
  unsigned short* Wb       = (unsigned short*)(ws + 68157440);  //  2,097,152 B

  k_prep<<<1536, 256, 0, stream>>>(ques, w_q, qw, fW, Wb);
  k_simpv<<<dim3(16, 32), 256, 0, stream>>>(ctx, ques, qw, w_c, w_m, rowmax, attended);
  k_q2c_softmax<<<32, 256, 0, stream>>>(rowmax, q2cw);
  k_q2c_part<<<dim3(8, 32), 256, 0, stream>>>(attended, q2cw, part);
  k_wmod<<<dim3(128, 32), 256, 0, stream>>>(Wb, part, attended);
  k_gemm<<<2048, 256, 0, stream>>>(attended, Wb, fb, mask, out);
}

// Round 14
// 151.551 us; speedup vs baseline: 1.1153x; 1.0500x over previous
//
#include <hip/hip_runtime.h>

// Problem constants
#define BB 32
#define CC 1024
#define QQ 64
#define EE 256
#define FE 1024
#define MM (BB*CC)   // 32768

typedef __bf16 bf16_t;
typedef bf16_t bf16x8 __attribute__((ext_vector_type(8)));
typedef float f32x4 __attribute__((ext_vector_type(4)));
typedef unsigned short u16x8 __attribute__((ext_vector_type(8)));

__device__ __forceinline__ unsigned short f2bf(float f) {
  unsigned u = __float_as_uint(f);
  u += 0x7fffu + ((u >> 16) & 1u);   // RNE
  return (unsigned short)(u >> 16);
}
__device__ __forceinline__ float bf2f(unsigned short u) {
  return __uint_as_float(((unsigned)u) << 16);
}

__device__ __forceinline__ void gload_lds16(const void* g, void* l) {
  __builtin_amdgcn_global_load_lds(
      (const __attribute__((address_space(1))) unsigned int*)g,
      (__attribute__((address_space(3))) unsigned int*)l, 16, 0, 0);
}

// ---------------------------------------------------------------- prep: qw = question.w_question; cast W to bf16
__global__ void k_prep(const float* __restrict__ question, const float* __restrict__ w_question,
                       float* __restrict__ qw,
                       const float* __restrict__ W, unsigned short* __restrict__ Wb) {
  int bx = blockIdx.x;
  if (bx < 512) {
    int gid = bx * 256 + threadIdx.x;
    int row = gid >> 6;            // (b*QQ + q), 0..2047
    int lane = gid & 63;
    const float4 q = *(const float4*)(question + (size_t)row * EE + lane * 4);
    const float4 wq = *(const float4*)(w_question + lane * 4);
    float d = q.x*wq.x + q.y*wq.y + q.z*wq.z + q.w*wq.w;
    d += __shfl_xor(d, 1);  d += __shfl_xor(d, 2);  d += __shfl_xor(d, 4);
    d += __shfl_xor(d, 8);  d += __shfl_xor(d, 16); d += __shfl_xor(d, 32);
    if (lane == 0) qw[row] = d;
  } else {
    int i = ((bx - 512) * 256 + threadIdx.x) * 4;
    float4 v = *(const float4*)(W + i);
    ushort4 o; o.x = f2bf(v.x); o.y = f2bf(v.y); o.z = f2bf(v.z); o.w = f2bf(v.w);
    *(ushort4*)(Wb + i) = o;
  }
}

#define DOT4(acc, A, Bv) acc += A.x*Bv.x + A.y*Bv.y + A.z*Bv.z + A.w*Bv.w

// ---------------------------------------------------------------- fused similarity + softmax + PV
__launch_bounds__(256)
__global__ void k_simpv(const float* __restrict__ ctx, const float* __restrict__ question,
                        const float* __restrict__ qw_g, const float* __restrict__ w_context,
                        const float* __restrict__ w_multiple,
                        float* __restrict__ rowmax, unsigned short* __restrict__ att) {
  __shared__ float qbuf[QQ * 132];          // sim: [q][128+4]; PV: [q][64+4]
  __shared__ float ck[64][36];              // ctx*w_mult chunk
  __shared__ unsigned short Pl[QQ][68];     // P[q][c] bf16
  __shared__ float cwl[64];
  __shared__ float qwl[QQ];
  const int tid = threadIdx.x;
  const int b = blockIdx.y;
  const int c0 = blockIdx.x * 64;
  const int tx = tid & 15, ty = tid >> 4;

  const float* qb = question + (size_t)b * (QQ * EE);
  if (tid < QQ) qwl[tid] = qw_g[b * QQ + tid];

  const int cr = tid >> 3, er = (tid & 7) * 4;
  const float* crow0 = ctx + ((size_t)(b * CC + c0 + cr)) * EE;
  const float* crow1 = crow0 + 32 * EE;
  unsigned short* arow0 = att + ((size_t)(b * CC + c0 + cr)) * FE;
  unsigned short* arow1 = arow0 + (size_t)32 * FE;
  float s[4][4] = {{0.f}};
  float cp0 = 0.f, cp1 = 0.f;

  for (int h = 0; h < 2; ++h) {
    if (h) __syncthreads();
    for (int idx = tid * 4; idx < QQ * 128; idx += 1024) {
      int row = idx >> 7, col = idx & 127;
      *(float4*)&qbuf[row * 132 + col] = *(const float4*)(qb + (size_t)row * EE + h * 128 + col);
    }
    for (int eo2 = 0; eo2 < 128; eo2 += 32) {
      const int eo = h * 128 + eo2;
      float4 cv0 = *(const float4*)(crow0 + eo + er);
      float4 cv1 = *(const float4*)(crow1 + eo + er);
      float4 wc = *(const float4*)(w_context + eo + er);
      float4 wm = *(const float4*)(w_multiple + eo + er);
      cp0 += cv0.x*wc.x + cv0.y*wc.y + cv0.z*wc.z + cv0.w*wc.w;
      cp1 += cv1.x*wc.x + cv1.y*wc.y + cv1.z*wc.z + cv1.w*wc.w;
      ushort4 u0, u1;
      u0.x = f2bf(cv0.x); u0.y = f2bf(cv0.y); u0.z = f2bf(cv0.z); u0.w = f2bf(cv0.w);
      u1.x = f2bf(cv1.x); u1.y = f2bf(cv1.y); u1.z = f2bf(cv1.z); u1.w = f2bf(cv1.w);
      *(ushort4*)(arow0 + eo + er) = u0;
      *(ushort4*)(arow1 + eo + er) = u1;
      __syncthreads();
      float4 m0, m1;
      m0.x = cv0.x*wm.x; m0.y = cv0.y*wm.y; m0.z = cv0.z*wm.z; m0.w = cv0.w*wm.w;
      m1.x = cv1.x*wm.x; m1.y = cv1.y*wm.y; m1.z = cv1.z*wm.z; m1.w = cv1.w*wm.w;
      *(float4*)&ck[cr][er] = m0;
      *(float4*)&ck[cr + 32][er] = m1;
      __syncthreads();
#pragma unroll
      for (int ee = 0; ee < 32; ee += 4) {
        float4 a0 = *(const float4*)&ck[ty +  0][ee];
        float4 a1 = *(const float4*)&ck[ty + 16][ee];
        float4 a2 = *(const float4*)&ck[ty + 32][ee];
        float4 a3 = *(const float4*)&ck[ty + 48][ee];
        float4 b0 = *(const float4*)&qbuf[(tx +  0) * 132 + eo2 + ee];
        float4 b1 = *(const float4*)&qbuf[(tx + 16) * 132 + eo2 + ee];
        float4 b2 = *(const float4*)&qbuf[(tx + 32) * 132 + eo2 + ee];
        float4 b3 = *(const float4*)&qbuf[(tx + 48) * 132 + eo2 + ee];
        DOT4(s[0][0], a0, b0); DOT4(s[0][1], a0, b1); DOT4(s[0][2], a0, b2); DOT4(s[0][3], a0, b3);
        DOT4(s[1][0], a1, b0); DOT4(s[1][1], a1, b1); DOT4(s[1][2], a1, b2); DOT4(s[1][3], a1, b3);
        DOT4(s[2][0], a2, b0); DOT4(s[2][1], a2, b1); DOT4(s[2][2], a2, b2); DOT4(s[2][3], a2, b3);
        DOT4(s[3][0], a3, b0); DOT4(s[3][1], a3, b1); DOT4(s[3][2], a3, b2); DOT4(s[3][3], a3, b3);
      }
    }
  }
  cp0 += __shfl_xor(cp0, 1); cp0 += __shfl_xor(cp0, 2); cp0 += __shfl_xor(cp0, 4);
  cp1 += __shfl_xor(cp1, 1); cp1 += __shfl_xor(cp1, 2); cp1 += __shfl_xor(cp1, 4);
  if ((tid & 7) == 0) { cwl[cr] = cp0; cwl[cr + 32] = cp1; }
  __syncthreads();

#pragma unroll
  for (int i = 0; i < 4; ++i) {
    int c = ty + 16 * i;
    float cw = cwl[c];
    float f[4], mx = -1e30f;
#pragma unroll
    for (int j = 0; j < 4; ++j) {
      f[j] = s[i][j] + cw + qwl[tx + 16 * j];
      mx = fmaxf(mx, f[j]);
    }
    mx = fmaxf(mx, __shfl_xor(mx, 1));
    mx = fmaxf(mx, __shfl_xor(mx, 2));
    mx = fmaxf(mx, __shfl_xor(mx, 4));
    mx = fmaxf(mx, __shfl_xor(mx, 8));
    float sum = 0.f;
#pragma unroll
    for (int j = 0; j < 4; ++j) { f[j] = expf(f[j] - mx); sum += f[j]; }
    sum += __shfl_xor(sum, 1);
    sum += __shfl_xor(sum, 2);
    sum += __shfl_xor(sum, 4);
    sum += __shfl_xor(sum, 8);
    float inv = 1.f / sum;
    if (tx == 0) rowmax[(size_t)b * CC + c0 + c] = mx;
#pragma unroll
    for (int j = 0; j < 4; ++j) Pl[tx + 16 * j][c] = f2bf(f[j] * inv);
  }
  __syncthreads();

  for (int ep = 0; ep < EE; ep += 64) {
    if (ep) __syncthreads();
    {
      int q = tid >> 2, e16 = (tid & 3) * 16;
      const float* src = qb + (size_t)q * EE + ep + e16;
      *(float4*)&qbuf[q * 68 + e16 +  0] = *(const float4*)(src);
      *(float4*)&qbuf[q * 68 + e16 +  4] = *(const float4*)(src + 4);
      *(float4*)&qbuf[q * 68 + e16 +  8] = *(const float4*)(src + 8);
      *(float4*)&qbuf[q * 68 + e16 + 12] = *(const float4*)(src + 12);
    }
    __syncthreads();
    float s2[4][4] = {{0.f}};
#pragma unroll 8
    for (int q = 0; q < QQ; ++q) {
      float a0 = bf2f(Pl[q][ty +  0]);
      float a1 = bf2f(Pl[q][ty + 16]);
      float a2 = bf2f(Pl[q][ty + 32]);
      float a3 = bf2f(Pl[q][ty + 48]);
      float4 bv = *(const float4*)&qbuf[q * 68 + tx * 4];
      s2[0][0] += a0 * bv.x; s2[0][1] += a0 * bv.y; s2[0][2] += a0 * bv.z; s2[0][3] += a0 * bv.w;
      s2[1][0] += a1 * bv.x; s2[1][1] += a1 * bv.y; s2[1][2] += a1 * bv.z; s2[1][3] += a1 * bv.w;
      s2[2][0] += a2 * bv.x; s2[2][1] += a2 * bv.y; s2[2][2] += a2 * bv.z; s2[2][3] += a2 * bv.w;
      s2[3][0] += a3 * bv.x; s2[3][1] += a3 * bv.y; s2[3][2] += a3 * bv.z; s2[3][3] += a3 * bv.w;
    }
#pragma unroll
    for (int i = 0; i < 4; ++i) {
      int c = ty + 16 * i;
      size_t row = (size_t)(b * CC + c0 + c);
      unsigned short* arow = att + row * (size_t)FE;
      ushort4 cu = *(const ushort4*)(arow + ep + tx * 4);
      float cx = bf2f(cu.x), cy = bf2f(cu.y), cz = bf2f(cu.z), cw = bf2f(cu.w);
      ushort4 o1, o2;
      o1.x = f2bf(s2[i][0]);       o1.y = f2bf(s2[i][1]);       o1.z = f2bf(s2[i][2]);       o1.w = f2bf(s2[i][3]);
      o2.x = f2bf(cx * s2[i][0]);  o2.y = f2bf(cy * s2[i][1]);  o2.z = f2bf(cz * s2[i][2]);  o2.w = f2bf(cw * s2[i][3]);
      *(ushort4*)(arow + 1 * EE + ep + tx * 4) = o1;
      *(ushort4*)(arow + 2 * EE + ep + tx * 4) = o2;
    }
  }
}

// ---------------------------------------------------------------- q2c partials (softmax folded in):
// each block recomputes softmax stats of rowmax[b][:] (4KB), then part = sum_c w[c]*att0
__global__ void k_q2c_part(const unsigned short* __restrict__ att, const float* __restrict__ rowmax,
                           float* __restrict__ part) {
  __shared__ float red[8];
  __shared__ float wl[128];
  const int b = blockIdx.y, ch = blockIdx.x, t = threadIdx.x;
  float4 v = *(const float4*)(rowmax + (size_t)b * CC + t * 4);
  float m = fmaxf(fmaxf(v.x, v.y), fmaxf(v.z, v.w));
  for (int off = 1; off < 64; off <<= 1) m = fmaxf(m, __shfl_xor(m, off));
  if ((t & 63) == 0) red[t >> 6] = m;
  __syncthreads();
  m = fmaxf(fmaxf(red[0], red[1]), fmaxf(red[2], red[3]));
  float s = expf(v.x - m) + expf(v.y - m) + expf(v.z - m) + expf(v.w - m);
  for (int off = 1; off < 64; off <<= 1) s += __shfl_xor(s, off);
  if ((t & 63) == 0) red[4 + (t >> 6)] = s;
  __syncthreads();
  float inv = 1.f / (red[4] + red[5] + red[6] + red[7]);
  if (t < 128) wl[t] = expf(rowmax[(size_t)b * CC + ch * 128 + t] - m) * inv;
  __syncthreads();
  const unsigned short* base = att + ((size_t)(b * CC + ch * 128)) * FE + t;
  float acc = 0.f;
#pragma unroll 4
  for (int c = 0; c < 128; ++c) acc += wl[c] * bf2f(base[(size_t)c * FE]);
  part[(b * 8 + ch) * EE + t] = acc;
}

// ---------------------------------------------------------------- Wmod: att[b*1024+n][768:1024] = bf16(W[n][e] + W[n][768+e]*q2c_b[e])
__global__ void k_wmod(const unsigned short* __restrict__ Wb, const float* __restrict__ part,
                       unsigned short* __restrict__ att) {
  __shared__ float q2cl[EE];
  const int b = blockIdx.y;
  const int t = threadIdx.x;
  {
    float a = 0.f;
#pragma unroll
    for (int ch = 0; ch < 8; ++ch) a += part[(b * 8 + ch) * EE + t];
    q2cl[t] = a;
  }
  __syncthreads();
  const int n = blockIdx.x * 8 + (t >> 5);
  const int e = (t & 31) * 8;
  u16x8 w1 = *(const u16x8*)(Wb + (size_t)n * FE + e);
  u16x8 w4 = *(const u16x8*)(Wb + (size_t)n * FE + 768 + e);
  float4 g0 = *(const float4*)&q2cl[e];
  float4 g1 = *(const float4*)&q2cl[e + 4];
  u16x8 o;
  o[0] = f2bf(bf2f(w1[0]) + bf2f(w4[0]) * g0.x);
  o[1] = f2bf(bf2f(w1[1]) + bf2f(w4[1]) * g0.y);
  o[2] = f2bf(bf2f(w1[2]) + bf2f(w4[2]) * g0.z);
  o[3] = f2bf(bf2f(w1[3]) + bf2f(w4[3]) * g0.w);
  o[4] = f2bf(bf2f(w1[4]) + bf2f(w4[4]) * g1.x);
  o[5] = f2bf(bf2f(w1[5]) + bf2f(w4[5]) * g1.y);
  o[6] = f2bf(bf2f(w1[6]) + bf2f(w4[6]) * g1.z);
  o[7] = f2bf(bf2f(w1[7]) + bf2f(w4[7]) * g1.w);
  *(u16x8*)(att + ((size_t)(b * CC + n)) * FE + 768 + e) = o;
}

// ---------------------------------------------------------------- final GEMM: out = A[:,0:768] @ B^T + bias, masked
// 128x128 tile, BK=64 (12 iters), single-buffered 32KB LDS, 4 waves, 2-barrier loop, 3 blk/CU.
// 3-bit XOR swizzle (128B rows — R4-R6-proven conflict-free). Vectorized LDS-transpose epilogue.
__launch_bounds__(256, 3)
__global__ void k_gemm(const unsigned short* __restrict__ A, const unsigned short* __restrict__ Bw,
                       const float* __restrict__ bias, const float* __restrict__ mask,
                       float* __restrict__ out) {
  __shared__ __align__(16) unsigned char LDSBUF[32768];
  bf16_t* As = (bf16_t*)LDSBUF;              // [128][64]
  bf16_t* Bs = As + 128 * 64;                // [128][64]
  float* sm = (float*)LDSBUF;                // epilogue overlay [32][133] = 17KB
  const int tid = threadIdx.x;
  const int lane = tid & 63;
  const int wave = tid >> 6;
  const int wr = wave >> 1, wc = wave & 1;

  // XCD-chunked swizzle: 2048 blocks, 8 XCDs -> 256 contiguous wgs per XCD.
  const int bid = blockIdx.x;
  const int wg = (bid & 7) * 256 + (bid >> 3);
  const int bcol = (wg & 7) * 128;
  const int brow = (wg >> 3) * 128;
  const int bb = brow >> 10;                // batch (128-row tile never crosses batch)

  const int r = lane & 15, kg = lane >> 4;

  // staging: 4 calls each for A,B; call i covers rows i*32 + (tid>>3), granule tid&7.
  // 128B rows -> 3-bit XOR key (row&7); dest linear, source pre-swizzled.
  const int srow = tid >> 3;                // 0..31 (call i adds i*32; (i*32)&7==0 keeps key)
  const int ssw = ((tid & 7) ^ (srow & 7)) * 8;
  const unsigned short* gA = A  + (size_t)(brow + srow) * FE + ssw;
  const unsigned short* gB = Bw + (size_t)(bcol + srow) * FE + ssw;
  const unsigned short* gW = A  + (size_t)(bb * CC + bcol + srow) * FE + 768 + ssw;  // Wmod_b
  bf16_t* dA = As + tid * 8;
  bf16_t* dB = Bs + tid * 8;

  f32x4 acc[4][4] = {};

  for (int k0 = 0; k0 < 768; k0 += 64) {
#pragma unroll
    for (int i = 0; i < 4; ++i)
      gload_lds16(gA + (size_t)(i * 32) * FE + k0, dA + i * 2048);
    if (k0 < 256) {
#pragma unroll
      for (int i = 0; i < 4; ++i)
        gload_lds16(gW + (size_t)(i * 32) * FE + k0, dB + i * 2048);
    } else {
#pragma unroll
      for (int i = 0; i < 4; ++i)
        gload_lds16(gB + (size_t)(i * 32) * FE + k0, dB + i * 2048);
    }
    __syncthreads();                       // drains vmcnt: tile ready

    bf16x8 fa[4][2], fb[4][2];
#pragma unroll
    for (int m = 0; m < 4; ++m) {
      const int row_ = wr * 64 + m * 16 + r;
#pragma unroll
      for (int ks = 0; ks < 2; ++ks)
        fa[m][ks] = *(const bf16x8*)(As + row_ * 64 + (((ks * 4 + kg) ^ (row_ & 7)) * 8));
    }
#pragma unroll
    for (int n = 0; n < 4; ++n) {
      const int row_ = wc * 64 + n * 16 + r;
#pragma unroll
      for (int ks = 0; ks < 2; ++ks)
        fb[n][ks] = *(const bf16x8*)(Bs + row_ * 64 + (((ks * 4 + kg) ^ (row_ & 7)) * 8));
    }
#pragma unroll
    for (int ks = 0; ks < 2; ++ks)
#pragma unroll
      for (int m = 0; m < 4; ++m)
#pragma unroll
        for (int n = 0; n < 4; ++n)
          acc[m][n] = __builtin_amdgcn_mfma_f32_16x16x32_bf16(fa[m][ks], fb[n][ks], acc[m][n], 0, 0, 0);
    __syncthreads();                       // all reads done before next-iter overwrite
  }

  // ---- vectorized epilogue: 4 chunks of 32 rows x 128 cols via LDS [32][133] ----
  const int lrow = tid >> 3;               // 0..31
  const int co = (tid & 7) * 4;            // col offset within 32-dword groups
#pragma unroll
  for (int m = 0; m < 4; ++m) {
    if (m) __syncthreads();                // chunk m-1 reads done before overwrite
#pragma unroll
    for (int n = 0; n < 4; ++n)
#pragma unroll
      for (int reg = 0; reg < 4; ++reg)
        sm[(wr * 16 + kg * 4 + reg) * 133 + wc * 64 + n * 16 + r] = acc[m][n][reg];
    __syncthreads();
    const int grow = brow + (lrow >> 4) * 64 + m * 16 + (lrow & 15);
    const float mk = mask[grow];
    float* orow = out + (size_t)grow * FE + bcol;
#pragma unroll
    for (int j = 0; j < 4; ++j) {
      const int c = co + j * 32;
      float4 v = *(float4*)&sm[lrow * 133 + c];
      float4 bz = *(const float4*)(bias + bcol + c);
      float4 o; o.x = (v.x + bz.x) * mk; o.y = (v.y + bz.y) * mk;
      o.z = (v.z + bz.z) * mk; o.w = (v.w + bz.w) * mk;
      *(float4*)(orow + c) = o;
    }
  }
}

// ---------------------------------------------------------------- launch
extern "C" void kernel_launch(void* const* d_in, const int* in_sizes, int n_in,
                              void* d_out, int out_size, void* d_ws, size_t ws_size,
                              hipStream_t stream) {
  const float* ctx  = (const float*)d_in[0];
  const float* ques = (const float*)d_in[1];
  const float* mask = (const float*)d_in[2];
  const float* w_q  = (const float*)d_in[3];
  const float* w_c  = (const float*)d_in[4];
  const float* w_m  = (const float*)d_in[5];
  const float* fW   = (const float*)d_in[6];
  const float* fb   = (const float*)d_in[7];
  float* out = (float*)d_out;

  char* ws = (char*)d_ws;
  float* qw     = (float*)(ws);                        //     8,192 B
  float* rowmax = (float*)(ws + 8192);                 //   131,072 B
  float* part   = (float*)(ws + 139264);               //   262,144 B
  unsigned short* attended = (unsigned short*)(ws + 1048576);   // 67,108,864 B (q3 holds Wmod)
  unsigned short* Wb       = (unsigned short*)(ws + 68157440);  //  2,097,152 B

  k_prep<<<1536, 256, 0, stream>>>(ques, w_q, qw, fW, Wb);
  k_simpv<<<dim3(16, 32), 256, 0, stream>>>(ctx, ques, qw, w_c, w_m, rowmax, attended);
  k_q2c_part<<<dim3(8, 32), 256, 0, stream>>>(attended, rowmax, part);
  k_wmod<<<dim3(128, 32), 256, 0, stream>>>(Wb, part, attended);
  k_gemm<<<2048, 256, 0, stream>>>(attended, Wb, fb, mask, out);
}